// Round 13
// baseline (621.845 us; speedup 1.0000x reference)
//
#include <hip/hip_runtime.h>
#include <cmath>
#include <cstdint>
#include <cstddef>

#define NB 8
#define NPTS 1024
#define BN (NB*NPTS)
#define KNN 20
#define XC_C 512
#define BN_SC 0.99999500003749973f  // 1/sqrt(1+1e-5)

static __device__ __forceinline__ float lrelu(float z) { return z >= 0.f ? z : 0.01f * z; }

// DPP-based max step on a (lo,hi) u64 — R2/R4-validated on HW.
// CTRL: row_ror:1/2/4/8 = 0x121/0x122/0x124/0x128, row_bcast15=0x142, row_bcast31=0x143.
// bound_ctrl=false + old=0 -> lanes with no source contribute 0 (= -inf sentinel).
template<int CTRL>
static __device__ __forceinline__ void dpp_max(unsigned& lo, unsigned& hi) {
    unsigned tlo = (unsigned)__builtin_amdgcn_update_dpp(0, (int)lo, CTRL, 0xF, 0xF, false);
    unsigned thi = (unsigned)__builtin_amdgcn_update_dpp(0, (int)hi, CTRL, 0xF, 0xF, false);
    unsigned long long a = ((unsigned long long)hi << 32) | lo;
    unsigned long long b = ((unsigned long long)thi << 32) | tlo;
    if (b > a) { lo = tlo; hi = thi; }
}

static __device__ __forceinline__ unsigned long long wave_max_u64(unsigned long long v) {
    unsigned lo = (unsigned)v, hi = (unsigned)(v >> 32);
    dpp_max<0x121>(lo, hi);
    dpp_max<0x122>(lo, hi);
    dpp_max<0x124>(lo, hi);
    dpp_max<0x128>(lo, hi);
    dpp_max<0x142>(lo, hi);   // row_bcast15
    dpp_max<0x143>(lo, hi);   // row_bcast31; lane63 = wave max
    unsigned wlo = (unsigned)__builtin_amdgcn_readlane((int)lo, 63);
    unsigned whi = (unsigned)__builtin_amdgcn_readlane((int)hi, 63);
    return ((unsigned long long)whi << 32) | wlo;
}

// ---- bf16 split helpers (RNE) ----
static __device__ __forceinline__ unsigned short f2bf(float f) {
    unsigned u = __float_as_uint(f);
    unsigned r = u + 0x7fffu + ((u >> 16) & 1u);
    return (unsigned short)(r >> 16);
}
static __device__ __forceinline__ float bf2f(unsigned short h) {
    return __uint_as_float(((unsigned)h) << 16);
}

typedef __attribute__((ext_vector_type(8))) short short8;
typedef __attribute__((ext_vector_type(4))) float floatx4;

// ---- prep: x (B,N,3) -> ft (B,3,N) + norms ----
__global__ void prep_k(const float* __restrict__ x, float* __restrict__ ft, float* __restrict__ nrm) {
    int i = blockIdx.x * 256 + threadIdx.x;   // b*N+n
    if (i >= BN) return;
    int b = i >> 10, n = i & 1023;
    float a = x[3*i], c = x[3*i+1], d = x[3*i+2];
    float* fb = ft + (size_t)b * 3 * NPTS;
    fb[n] = a; fb[NPTS + n] = c; fb[2*NPTS + n] = d;
    nrm[i] = a*a + c*c + d*d;
}

// ---- fused knn: ONE row per wave (max TLP: grid BN/4 = 2048 blocks = 32 waves/CU).
// Distance phase: R2-validated single-row form. Selection: R12-validated sorted rounds
// with R4-validated single-chain wave_max_u64. Keys: hi = order-preserving u32 of
// (2*inner - xx[m]); lo = 1023-m; all real keys > 0 so 0 is a safe -inf sentinel.
// Pop order = u64 desc == (value desc, m asc) == jax top_k order. Bit-identical output.
template<int C>
__global__ __launch_bounds__(256) void knn_k(const float* __restrict__ ft,
                                             const float* __restrict__ frow, int frs,
                                             const float* __restrict__ nrm,
                                             int* __restrict__ idx) {
    int w = threadIdx.x >> 6;
    int lane = threadIdx.x & 63;
    int r = blockIdx.x * 4 + w;
    int b = r >> 10;
    const float* ftb = ft + (size_t)b * C * NPTS;

    float4 acc[4];
#pragma unroll
    for (int j = 0; j < 4; j++) acc[j] = make_float4(0.f, 0.f, 0.f, 0.f);

    if constexpr ((C & 3) == 0) {
        const float4* cr = (const float4*)(frow + (size_t)r * frs);
        for (int c4 = 0; c4 < C/4; c4++) {
            float4 ct4 = cr[c4];
#pragma unroll
            for (int cc = 0; cc < 4; cc++) {
                float ctr = (&ct4.x)[cc];
                const float4* rm = (const float4*)(ftb + (size_t)(4*c4+cc) * NPTS);
#pragma unroll
                for (int j = 0; j < 4; j++) {
                    float4 v = rm[lane + 64*j];
                    acc[j].x = fmaf(ctr, v.x, acc[j].x);
                    acc[j].y = fmaf(ctr, v.y, acc[j].y);
                    acc[j].z = fmaf(ctr, v.z, acc[j].z);
                    acc[j].w = fmaf(ctr, v.w, acc[j].w);
                }
            }
        }
    } else {
        for (int c = 0; c < C; c++) {
            float ctr = frow[(size_t)r * frs + c];
            const float4* rm = (const float4*)(ftb + (size_t)c * NPTS);
#pragma unroll
            for (int j = 0; j < 4; j++) {
                float4 v = rm[lane + 64*j];
                acc[j].x = fmaf(ctr, v.x, acc[j].x);
                acc[j].y = fmaf(ctr, v.y, acc[j].y);
                acc[j].z = fmaf(ctr, v.z, acc[j].z);
                acc[j].w = fmaf(ctr, v.w, acc[j].w);
            }
        }
    }

    unsigned long long key[16];
    const float4* nm4 = (const float4*)(nrm + b * NPTS);
#pragma unroll
    for (int j = 0; j < 4; j++) {
        float4 nm = nm4[lane + 64*j];
#pragma unroll
        for (int q = 0; q < 4; q++) {
            int m = 4*(lane + 64*j) + q;
            float f = 2.f * (&acc[j].x)[q] - (&nm.x)[q];
            unsigned u = __float_as_uint(f);
            unsigned s = (unsigned)((int)u >> 31);
            u ^= (s | 0x80000000u);
            key[4*j+q] = ((unsigned long long)u << 32) | (unsigned)(1023 - m);
        }
    }

    // bitonic sort descending (R12-validated; constexpr indices, stays in registers)
#pragma unroll
    for (int ksz = 2; ksz <= 16; ksz <<= 1) {
#pragma unroll
        for (int jst = ksz >> 1; jst > 0; jst >>= 1) {
#pragma unroll
            for (int i = 0; i < 16; i++) {
                int l = i ^ jst;
                if (l > i) {
                    bool dsc = (i & ksz) == 0;
                    unsigned long long a = key[i], bb = key[l];
                    bool sw = dsc ? (a < bb) : (a > bb);
                    if (sw) { key[i] = bb; key[l] = a; }
                }
            }
        }
    }

    int mine = 0;
    for (int kk = 0; kk < KNN; kk++) {       // not unrolled
        unsigned long long win = wave_max_u64(key[0]);   // heads are local maxima
        if (lane == kk) mine = 1023 - (int)(unsigned)win;
        bool pop = (key[0] == win);          // unique keys -> exactly one lane pops
#pragma unroll
        for (int t = 0; t < 15; t++) key[t] = pop ? key[t+1] : key[t];
        key[15] = pop ? 0ull : key[15];
    }
    if (lane < KNN) idx[r * KNN + lane] = mine;
}

// ---- H/Ct GEMM: Ht[n,o]=F.w1; Ct[n,o]=F.w2 - Ht + bias ----
template<int C, int O, bool HASB>
__global__ void hc_k(const float* __restrict__ F, int FS,
                     const float* __restrict__ w, const float* __restrict__ bias,
                     float* __restrict__ Ht, float* __restrict__ Ct) {
    int r0 = blockIdx.x * 4;
    int o = threadIdx.x;
    const float* wr = w + (size_t)o * (2*C);
    float h[4] = {0,0,0,0}, a2[4] = {0,0,0,0};
    if constexpr ((C & 3) == 0) {
        const float4* w1 = (const float4*)wr;
        const float4* w2 = (const float4*)(wr + C);
#pragma unroll 4
        for (int c4 = 0; c4 < C/4; c4++) {
            float4 wa = w1[c4], wb = w2[c4];
#pragma unroll
            for (int nn = 0; nn < 4; nn++) {
                float4 f = *(const float4*)(F + (size_t)(r0+nn)*FS + 4*c4);  // broadcast
                h[nn]  = fmaf(wa.x,f.x, fmaf(wa.y,f.y, fmaf(wa.z,f.z, fmaf(wa.w,f.w, h[nn]))));
                a2[nn] = fmaf(wb.x,f.x, fmaf(wb.y,f.y, fmaf(wb.z,f.z, fmaf(wb.w,f.w, a2[nn]))));
            }
        }
    } else {
        for (int c = 0; c < C; c++) {
            float wa = wr[c], wb = wr[C+c];
#pragma unroll
            for (int nn = 0; nn < 4; nn++) {
                float f = F[(size_t)(r0+nn)*FS + c];
                h[nn]  = fmaf(wa, f, h[nn]);
                a2[nn] = fmaf(wb, f, a2[nn]);
            }
        }
    }
    float bs = 0.f;
    if constexpr (HASB) bs = bias[o];
#pragma unroll
    for (int nn = 0; nn < 4; nn++) {
        size_t ro = (size_t)(r0+nn)*O + o;
        Ht[ro] = h[nn];
        Ct[ro] = a2[nn] - h[nn] + bs;
    }
}

// ---- gather + max_k + bn + lrelu; optional transposed-feature + norms for next knn ----
template<int O, bool WFT>
__global__ void gmax_k(const float* __restrict__ Ht, const float* __restrict__ Ct,
                       const int* __restrict__ idx,
                       const float* __restrict__ g, const float* __restrict__ bb,
                       float* __restrict__ xcs, float* __restrict__ ft, float* __restrict__ nrm) {
    int r = blockIdx.x;
    int b = r >> 10, n = r & 1023;
    int o = threadIdx.x;
    const int* id = idx + r * KNN;
    float vmax = -INFINITY, vmin = INFINITY;
    const float* hb = Ht + (size_t)b * NPTS * O + o;
#pragma unroll 4
    for (int k = 0; k < KNN; k++) {
        int m = id[k];                 // broadcast
        float v = hb[(size_t)m * O];   // coalesced across o
        vmax = fmaxf(vmax, v); vmin = fminf(vmin, v);
    }
    float ct = Ct[(size_t)r * O + o];
    float s = g[o] * BN_SC;
    float pre = (s >= 0.f ? vmax : vmin) + ct;
    float out = lrelu(fmaf(s, pre, bb[o]));
    xcs[(size_t)r * XC_C + o] = out;
    if constexpr (WFT) {
        ft[((size_t)b * O + o) * NPTS + n] = out;
        float sq = out * out;
#pragma unroll
        for (int off = 32; off > 0; off >>= 1) sq += __shfl_xor(sq, off);
        __shared__ float red[O/64 > 0 ? O/64 : 1];
        if ((o & 63) == 0) red[o >> 6] = sq;
        __syncthreads();
        if (o == 0) {
            float t = 0.f;
#pragma unroll
            for (int i = 0; i < O/64; i++) t += red[i];
            nrm[r] = t;
        }
    }
}

// ---- split-bf16 conversions for conv5 MFMA ----
__global__ void xcvt_k(const float* __restrict__ xc,
                       unsigned short* __restrict__ xh, unsigned short* __restrict__ xl) {
    int i = blockIdx.x * 256 + threadIdx.x;   // BN*512
    float v = xc[i];
    unsigned short h = f2bf(v);
    xh[i] = h;
    xl[i] = f2bf(v - bf2f(h));
}

__global__ void wcvt_k(const float* __restrict__ w5,
                       unsigned short* __restrict__ wh, unsigned short* __restrict__ wl) {
    int i = blockIdx.x * 256 + threadIdx.x;   // 1024*512, (o,c) row-major kept
    float v = w5[i];
    unsigned short h = f2bf(v);
    wh[i] = h;
    wl[i] = f2bf(v - bf2f(h));
}

// ---- conv5 via LDS-staged split-bf16 MFMA + in-tile max over n (R11, passing, absmax 0.0) ----
__global__ __launch_bounds__(256) void conv5mfma_k(const unsigned short* __restrict__ xh,
                                                   const unsigned short* __restrict__ xl,
                                                   const unsigned short* __restrict__ wh,
                                                   const unsigned short* __restrict__ wl,
                                                   float* __restrict__ part) {
    __shared__ short ah_s[32*72];
    __shared__ short al_s[32*72];
    __shared__ short bh_s[128*72];
    __shared__ short bl_s[128*72];
    int b = blockIdx.z, og = blockIdx.y, nt = blockIdx.x;   // nt 0..31, og 0..7
    int tid = threadIdx.x;
    int w = tid >> 6, lane = tid & 63;
    int m = lane & 15, quad = lane >> 4;
    int h = w >> 1, q = w & 1;
    size_t nbase = (size_t)b * NPTS + nt * 32;
    int obase = og * 128;
    int srow = tid >> 3;          // 0..31
    int scol = (tid & 7) * 8;     // 0,8,...,56 (shorts)

    floatx4 acc[4];
#pragma unroll
    for (int t = 0; t < 4; t++) acc[t] = (floatx4){0.f, 0.f, 0.f, 0.f};

    for (int kc = 0; kc < 512; kc += 64) {
        __syncthreads();   // previous-chunk readers done before overwrite
        *(short8*)(ah_s + srow*72 + scol) = *(const short8*)(xh + (nbase + srow)*512 + kc + scol);
        *(short8*)(al_s + srow*72 + scol) = *(const short8*)(xl + (nbase + srow)*512 + kc + scol);
#pragma unroll
        for (int i = 0; i < 4; i++) {
            int r = srow + i*32;
            *(short8*)(bh_s + r*72 + scol) = *(const short8*)(wh + (size_t)(obase + r)*512 + kc + scol);
            *(short8*)(bl_s + r*72 + scol) = *(const short8*)(wl + (size_t)(obase + r)*512 + kc + scol);
        }
        __syncthreads();
#pragma unroll
        for (int kk = 0; kk < 2; kk++) {
            short8 ah8 = *(const short8*)(ah_s + (h*16 + m)*72 + kk*32 + quad*8);
            short8 al8 = *(const short8*)(al_s + (h*16 + m)*72 + kk*32 + quad*8);
#pragma unroll
            for (int t = 0; t < 4; t++) {
                short8 bh8 = *(const short8*)(bh_s + (q*64 + t*16 + m)*72 + kk*32 + quad*8);
                short8 bl8 = *(const short8*)(bl_s + (q*64 + t*16 + m)*72 + kk*32 + quad*8);
                acc[t] = __builtin_amdgcn_mfma_f32_16x16x32_bf16(ah8, bh8, acc[t], 0, 0, 0);
                acc[t] = __builtin_amdgcn_mfma_f32_16x16x32_bf16(ah8, bl8, acc[t], 0, 0, 0);
                acc[t] = __builtin_amdgcn_mfma_f32_16x16x32_bf16(al8, bh8, acc[t], 0, 0, 0);
            }
        }
    }
#pragma unroll
    for (int t = 0; t < 4; t++) {
        float v = fmaxf(fmaxf(acc[t][0], acc[t][1]), fmaxf(acc[t][2], acc[t][3]));
        v = fmaxf(v, __shfl_xor(v, 16));
        v = fmaxf(v, __shfl_xor(v, 32));
        if (quad == 0)
            part[((size_t)b * 64 + nt*2 + h) * 1024 + obase + q*64 + t*16 + m] = v;
    }
}

// ---- global max pool: gp[b,o] = max_j part[b,j,o] ----
__global__ void gpool_k(const float* __restrict__ part, float* __restrict__ gp) {
    int i = blockIdx.x * 256 + threadIdx.x;   // b*1024+o
    int b = i >> 10, o = i & 1023;
    const float* pb = part + (size_t)b * 64 * 1024 + o;
    float m = pb[0];
#pragma unroll 4
    for (int j = 1; j < 64; j++) m = fmaxf(m, pb[(size_t)j * 1024]);
    gp[i] = m;
}

// ---- linear layer, one wave per output dot ----
template<int C, bool HASBIAS, bool ACT>
__global__ __launch_bounds__(256) void lin_k(const float* __restrict__ X, int xs,
                                             const float* __restrict__ W,
                                             const float* __restrict__ bias,
                                             const float* __restrict__ g, const float* __restrict__ bb,
                                             float* __restrict__ Y, int ys) {
    int wid = (blockIdx.x * 256 + threadIdx.x) >> 6;
    int lane = threadIdx.x & 63;
    int o = wid >> 3;          // NB = 8
    int b = wid & 7;
    const float4* wr = (const float4*)(W + (size_t)o * C);
    const float4* xr = (const float4*)(X + (size_t)b * xs);
    float acc = 0.f;
#pragma unroll
    for (int i = 0; i < C/256; i++) {
        float4 w = wr[lane + 64*i];
        float4 xv = xr[lane + 64*i];
        acc = fmaf(w.x,xv.x, fmaf(w.y,xv.y, fmaf(w.z,xv.z, fmaf(w.w,xv.w, acc))));
    }
#pragma unroll
    for (int off = 32; off > 0; off >>= 1) acc += __shfl_xor(acc, off);
    if (lane == 0) {
        if constexpr (HASBIAS) acc += bias[o];
        if constexpr (ACT) acc = lrelu(fmaf(acc, g[o] * BN_SC, bb[o]));
        Y[(size_t)b * ys + o] = acc;
    }
}

extern "C" void kernel_launch(void* const* d_in, const int* in_sizes, int n_in,
                              void* d_out, int out_size, void* d_ws, size_t ws_size,
                              hipStream_t stream) {
    const float* x       = (const float*)d_in[0];
    const float* conv1_w = (const float*)d_in[1];
    const float* conv1_b = (const float*)d_in[2];
    const float* bn1_g   = (const float*)d_in[3];
    const float* bn1_b   = (const float*)d_in[4];
    const float* conv2_w = (const float*)d_in[5];
    const float* bn2_g   = (const float*)d_in[6];
    const float* bn2_b   = (const float*)d_in[7];
    const float* conv3_w = (const float*)d_in[8];
    const float* bn3_g   = (const float*)d_in[9];
    const float* bn3_b   = (const float*)d_in[10];
    const float* conv4_w = (const float*)d_in[11];
    const float* bn4_g   = (const float*)d_in[12];
    const float* bn4_b   = (const float*)d_in[13];
    const float* conv5_w = (const float*)d_in[14];
    const float* lin1_w  = (const float*)d_in[15];
    const float* bn6_g   = (const float*)d_in[16];
    const float* bn6_b   = (const float*)d_in[17];
    const float* lin2_w  = (const float*)d_in[18];
    const float* lin2_b  = (const float*)d_in[19];
    const float* bn7_g   = (const float*)d_in[20];
    const float* bn7_b   = (const float*)d_in[21];
    const float* lin3_w  = (const float*)d_in[22];
    const float* lin3_b  = (const float*)d_in[23];
    float* outp = (float*)d_out;

    // workspace layout (floats): total 10,657,792 f = 42.6 MB
    float* ws   = (float*)d_ws;
    float* xc   = ws;                          // (BN,512)          4,194,304
    int*   idxb = (int*)(ws + 4194304);        // (BN,20)             163,840
    float* nrm  = ws + 4194304 + 163840;       // (BN)                  8,192
    float* ft   = nrm + 8192;                  // (B,<=128,N)       1,048,576
    float* part = ft + 1048576;                // (B,64,1024)         524,288
    float* w5t  = part + 524288;               // bf16 wh/wl          524,288
    float* Ht   = w5t + 524288;                // (BN,<=256) / xh   2,097,152
    float* Ct   = Ht + 2097152;                // (BN,<=256) / xl   2,097,152
    // head scratch aliases ft (dead after the last knn_k):
    float* gp   = ft;                          // (8,1024)
    float* y1   = ft + 8192;                   // (8,512)
    float* y2   = ft + 8192 + 4096;            // (8,256)
    // split-bf16 aliases (dead regions after stage 4):
    unsigned short* xhp = (unsigned short*)Ht;       // BN*512 shorts
    unsigned short* xlp = (unsigned short*)Ct;
    unsigned short* whp = (unsigned short*)w5t;      // 1024*512 shorts
    unsigned short* wlp = whp + 1024*512;

    prep_k<<<BN/256, 256, 0, stream>>>(x, ft, nrm);

    // Stage 1: C=3 (coords), O=64, with conv bias
    knn_k<3><<<BN/4, 256, 0, stream>>>(ft, x, 3, nrm, idxb);
    hc_k<3, 64, true><<<BN/4, 64, 0, stream>>>(x, 3, conv1_w, conv1_b, Ht, Ct);
    gmax_k<64, true><<<BN, 64, 0, stream>>>(Ht, Ct, idxb, bn1_g, bn1_b, xc + 0, ft, nrm);

    // Stage 2: C=64 -> O=64
    knn_k<64><<<BN/4, 256, 0, stream>>>(ft, xc + 0, XC_C, nrm, idxb);
    hc_k<64, 64, false><<<BN/4, 64, 0, stream>>>(xc + 0, XC_C, conv2_w, nullptr, Ht, Ct);
    gmax_k<64, true><<<BN, 64, 0, stream>>>(Ht, Ct, idxb, bn2_g, bn2_b, xc + 64, ft, nrm);

    // Stage 3: C=64 -> O=128
    knn_k<64><<<BN/4, 256, 0, stream>>>(ft, xc + 64, XC_C, nrm, idxb);
    hc_k<64, 128, false><<<BN/4, 128, 0, stream>>>(xc + 64, XC_C, conv3_w, nullptr, Ht, Ct);
    gmax_k<128, true><<<BN, 128, 0, stream>>>(Ht, Ct, idxb, bn3_g, bn3_b, xc + 128, ft, nrm);

    // Stage 4: C=128 -> O=256 (no next knn)
    knn_k<128><<<BN/4, 256, 0, stream>>>(ft, xc + 128, XC_C, nrm, idxb);
    hc_k<128, 256, false><<<BN/4, 256, 0, stream>>>(xc + 128, XC_C, conv4_w, nullptr, Ht, Ct);
    gmax_k<256, false><<<BN, 256, 0, stream>>>(Ht, Ct, idxb, bn4_g, bn4_b, xc + 256, nullptr, nullptr);

    // conv5 via LDS-staged split-bf16 MFMA + global max pool + parallel head
    xcvt_k<<<BN*512/256, 256, 0, stream>>>(xc, xhp, xlp);
    wcvt_k<<<1024*512/256, 256, 0, stream>>>(conv5_w, whp, wlp);
    conv5mfma_k<<<dim3(32, 8, NB), 256, 0, stream>>>(xhp, xlp, whp, wlp, part);
    gpool_k<<<NB*1024/256, 256, 0, stream>>>(part, gp);
    lin_k<1024, false, true><<<NB*512/4, 256, 0, stream>>>(gp, 1024, lin1_w, nullptr, bn6_g, bn6_b, y1, 512);
    lin_k<512,  true,  true><<<NB*256/4, 256, 0, stream>>>(y1, 512, lin2_w, lin2_b, bn7_g, bn7_b, y2, 256);
    lin_k<256,  true, false><<<NB*40/4,  256, 0, stream>>>(y2, 256, lin3_w, lin3_b, nullptr, nullptr, outp, 40);
}

// Round 14
// 578.448 us; speedup vs baseline: 1.0750x; 1.0750x over previous
//
#include <hip/hip_runtime.h>
#include <cmath>
#include <cstdint>
#include <cstddef>

#define NB 8
#define NPTS 1024
#define BN (NB*NPTS)
#define KNN 20
#define XC_C 512
#define BN_SC 0.99999500003749973f  // 1/sqrt(1+1e-5)

static __device__ __forceinline__ float lrelu(float z) { return z >= 0.f ? z : 0.01f * z; }

// DPP-based max step on a (lo,hi) u64 — R2/R4/R13-validated on HW.
// CTRL: row_ror:1/2/4/8 = 0x121/0x122/0x124/0x128, row_bcast15=0x142, row_bcast31=0x143.
// bound_ctrl=false + old=0 -> lanes with no source contribute 0 (= -inf sentinel).
template<int CTRL>
static __device__ __forceinline__ void dpp_max(unsigned& lo, unsigned& hi) {
    unsigned tlo = (unsigned)__builtin_amdgcn_update_dpp(0, (int)lo, CTRL, 0xF, 0xF, false);
    unsigned thi = (unsigned)__builtin_amdgcn_update_dpp(0, (int)hi, CTRL, 0xF, 0xF, false);
    unsigned long long a = ((unsigned long long)hi << 32) | lo;
    unsigned long long b = ((unsigned long long)thi << 32) | tlo;
    if (b > a) { lo = tlo; hi = thi; }
}

static __device__ __forceinline__ unsigned long long wave_max_u64(unsigned long long v) {
    unsigned lo = (unsigned)v, hi = (unsigned)(v >> 32);
    dpp_max<0x121>(lo, hi);
    dpp_max<0x122>(lo, hi);
    dpp_max<0x124>(lo, hi);
    dpp_max<0x128>(lo, hi);
    dpp_max<0x142>(lo, hi);   // row_bcast15
    dpp_max<0x143>(lo, hi);   // row_bcast31; lane63 = wave max
    unsigned wlo = (unsigned)__builtin_amdgcn_readlane((int)lo, 63);
    unsigned whi = (unsigned)__builtin_amdgcn_readlane((int)hi, 63);
    return ((unsigned long long)whi << 32) | wlo;
}

// ---- bf16 split helpers (RNE) ----
static __device__ __forceinline__ unsigned short f2bf(float f) {
    unsigned u = __float_as_uint(f);
    unsigned r = u + 0x7fffu + ((u >> 16) & 1u);
    return (unsigned short)(r >> 16);
}
static __device__ __forceinline__ float bf2f(unsigned short h) {
    return __uint_as_float(((unsigned)h) << 16);
}

typedef __attribute__((ext_vector_type(8))) short short8;
typedef __attribute__((ext_vector_type(4))) float floatx4;

// ---- prep: x (B,N,3) -> ft (B,3,N) + norms ----
__global__ void prep_k(const float* __restrict__ x, float* __restrict__ ft, float* __restrict__ nrm) {
    int i = blockIdx.x * 256 + threadIdx.x;   // b*N+n
    if (i >= BN) return;
    int b = i >> 10, n = i & 1023;
    float a = x[3*i], c = x[3*i+1], d = x[3*i+2];
    float* fb = ft + (size_t)b * 3 * NPTS;
    fb[n] = a; fb[NPTS + n] = c; fb[2*NPTS + n] = d;
    nrm[i] = a*a + c*c + d*d;
}

// ---- fused knn: TWO rows per wave (R12 structure, 557us-validated), selection via
// per-lane SORTED lists with the two rows STAGGERED half a round so each row's
// pop/shift (independent VALU work) fills the other row's DPP-chain latency.
// Keys: hi = order-preserving u32 of (2*inner - xx[m]); lo = 1023-m; all real keys > 0
// so 0 is a safe -inf sentinel. Pop order = u64 desc == (value desc, m asc) == jax order.
// Per-row semantics identical to R12 => bit-identical output.
template<int C>
__global__ __launch_bounds__(256) void knn_k(const float* __restrict__ ft,
                                             const float* __restrict__ frow, int frs,
                                             const float* __restrict__ nrm,
                                             int* __restrict__ idx) {
    int w = threadIdx.x >> 6;
    int lane = threadIdx.x & 63;
    int rA = blockIdx.x * 8 + 2 * w;
    int rB = rA + 1;
    int b = rA >> 10;                       // same batch for both rows (8 | 1024)
    const float* ftb = ft + (size_t)b * C * NPTS;

    float4 accA[4], accB[4];
#pragma unroll
    for (int j = 0; j < 4; j++) { accA[j] = make_float4(0.f,0.f,0.f,0.f); accB[j] = make_float4(0.f,0.f,0.f,0.f); }

    if constexpr ((C & 3) == 0) {
        const float4* crA = (const float4*)(frow + (size_t)rA * frs);
        const float4* crB = (const float4*)(frow + (size_t)rB * frs);
        for (int c4 = 0; c4 < C/4; c4++) {
            float4 ctA = crA[c4], ctB = crB[c4];
#pragma unroll
            for (int cc = 0; cc < 4; cc++) {
                float cA = (&ctA.x)[cc], cB = (&ctB.x)[cc];
                const float4* rm = (const float4*)(ftb + (size_t)(4*c4+cc) * NPTS);
#pragma unroll
                for (int j = 0; j < 4; j++) {
                    float4 v = rm[lane + 64*j];          // shared m-stream for both rows
                    accA[j].x = fmaf(cA, v.x, accA[j].x);
                    accA[j].y = fmaf(cA, v.y, accA[j].y);
                    accA[j].z = fmaf(cA, v.z, accA[j].z);
                    accA[j].w = fmaf(cA, v.w, accA[j].w);
                    accB[j].x = fmaf(cB, v.x, accB[j].x);
                    accB[j].y = fmaf(cB, v.y, accB[j].y);
                    accB[j].z = fmaf(cB, v.z, accB[j].z);
                    accB[j].w = fmaf(cB, v.w, accB[j].w);
                }
            }
        }
    } else {
        for (int c = 0; c < C; c++) {
            float cA = frow[(size_t)rA * frs + c];
            float cB = frow[(size_t)rB * frs + c];
            const float4* rm = (const float4*)(ftb + (size_t)c * NPTS);
#pragma unroll
            for (int j = 0; j < 4; j++) {
                float4 v = rm[lane + 64*j];
                accA[j].x = fmaf(cA, v.x, accA[j].x);
                accA[j].y = fmaf(cA, v.y, accA[j].y);
                accA[j].z = fmaf(cA, v.z, accA[j].z);
                accA[j].w = fmaf(cA, v.w, accA[j].w);
                accB[j].x = fmaf(cB, v.x, accB[j].x);
                accB[j].y = fmaf(cB, v.y, accB[j].y);
                accB[j].z = fmaf(cB, v.z, accB[j].z);
                accB[j].w = fmaf(cB, v.w, accB[j].w);
            }
        }
    }

    unsigned long long keyA[16], keyB[16];
    const float4* nm4 = (const float4*)(nrm + b * NPTS);
#pragma unroll
    for (int j = 0; j < 4; j++) {
        float4 nm = nm4[lane + 64*j];                    // shared for both rows
#pragma unroll
        for (int q = 0; q < 4; q++) {
            int m = 4*(lane + 64*j) + q;
            float fA = 2.f * (&accA[j].x)[q] - (&nm.x)[q];
            unsigned uA = __float_as_uint(fA);
            unsigned sA = (unsigned)((int)uA >> 31);
            uA ^= (sA | 0x80000000u);
            keyA[4*j+q] = ((unsigned long long)uA << 32) | (unsigned)(1023 - m);
            float fB = 2.f * (&accB[j].x)[q] - (&nm.x)[q];
            unsigned uB = __float_as_uint(fB);
            unsigned sB = (unsigned)((int)uB >> 31);
            uB ^= (sB | 0x80000000u);
            keyB[4*j+q] = ((unsigned long long)uB << 32) | (unsigned)(1023 - m);
        }
    }

    // bitonic sort both 16-lists descending (R12-validated; constexpr indices)
#pragma unroll
    for (int ksz = 2; ksz <= 16; ksz <<= 1) {
#pragma unroll
        for (int jst = ksz >> 1; jst > 0; jst >>= 1) {
#pragma unroll
            for (int i = 0; i < 16; i++) {
                int l = i ^ jst;
                if (l > i) {
                    bool dsc = (i & ksz) == 0;
                    unsigned long long a = keyA[i], bb = keyA[l];
                    bool swA = dsc ? (a < bb) : (a > bb);
                    if (swA) { keyA[i] = bb; keyA[l] = a; }
                    unsigned long long c = keyB[i], d = keyB[l];
                    bool swB = dsc ? (c < d) : (c > d);
                    if (swB) { keyB[i] = d; keyB[l] = c; }
                }
            }
        }
    }

    // staggered rounds: row A half a round ahead of row B, so each row's pop/shift
    // (independent VALU work) overlaps the other row's serial DPP chain.
    int mineA = 0, mineB = 0;
    unsigned long long winA = wave_max_u64(keyA[0]);     // prologue: round-0 chain for A
    for (int kk = 0; kk < KNN; kk++) {                   // not unrolled
        unsigned long long winB = wave_max_u64(keyB[0]); // overlaps A's pop/shift below
        if (lane == kk) mineA = 1023 - (int)(unsigned)winA;
        bool popA = (keyA[0] == winA);
#pragma unroll
        for (int t = 0; t < 15; t++) keyA[t] = popA ? keyA[t+1] : keyA[t];
        keyA[15] = popA ? 0ull : keyA[15];
        unsigned long long winAn = wave_max_u64(keyA[0]); // next A round; overlaps B's pop/shift
        if (lane == kk) mineB = 1023 - (int)(unsigned)winB;
        bool popB = (keyB[0] == winB);
#pragma unroll
        for (int t = 0; t < 15; t++) keyB[t] = popB ? keyB[t+1] : keyB[t];
        keyB[15] = popB ? 0ull : keyB[15];
        winA = winAn;                                    // last iteration's extra chain unused
    }
    if (lane < KNN) {
        idx[rA * KNN + lane] = mineA;
        idx[rB * KNN + lane] = mineB;
    }
}

// ---- H/Ct GEMM: Ht[n,o]=F.w1; Ct[n,o]=F.w2 - Ht + bias ----
template<int C, int O, bool HASB>
__global__ void hc_k(const float* __restrict__ F, int FS,
                     const float* __restrict__ w, const float* __restrict__ bias,
                     float* __restrict__ Ht, float* __restrict__ Ct) {
    int r0 = blockIdx.x * 4;
    int o = threadIdx.x;
    const float* wr = w + (size_t)o * (2*C);
    float h[4] = {0,0,0,0}, a2[4] = {0,0,0,0};
    if constexpr ((C & 3) == 0) {
        const float4* w1 = (const float4*)wr;
        const float4* w2 = (const float4*)(wr + C);
#pragma unroll 4
        for (int c4 = 0; c4 < C/4; c4++) {
            float4 wa = w1[c4], wb = w2[c4];
#pragma unroll
            for (int nn = 0; nn < 4; nn++) {
                float4 f = *(const float4*)(F + (size_t)(r0+nn)*FS + 4*c4);  // broadcast
                h[nn]  = fmaf(wa.x,f.x, fmaf(wa.y,f.y, fmaf(wa.z,f.z, fmaf(wa.w,f.w, h[nn]))));
                a2[nn] = fmaf(wb.x,f.x, fmaf(wb.y,f.y, fmaf(wb.z,f.z, fmaf(wb.w,f.w, a2[nn]))));
            }
        }
    } else {
        for (int c = 0; c < C; c++) {
            float wa = wr[c], wb = wr[C+c];
#pragma unroll
            for (int nn = 0; nn < 4; nn++) {
                float f = F[(size_t)(r0+nn)*FS + c];
                h[nn]  = fmaf(wa, f, h[nn]);
                a2[nn] = fmaf(wb, f, a2[nn]);
            }
        }
    }
    float bs = 0.f;
    if constexpr (HASB) bs = bias[o];
#pragma unroll
    for (int nn = 0; nn < 4; nn++) {
        size_t ro = (size_t)(r0+nn)*O + o;
        Ht[ro] = h[nn];
        Ct[ro] = a2[nn] - h[nn] + bs;
    }
}

// ---- gather + max_k + bn + lrelu; optional transposed-feature + norms for next knn ----
template<int O, bool WFT>
__global__ void gmax_k(const float* __restrict__ Ht, const float* __restrict__ Ct,
                       const int* __restrict__ idx,
                       const float* __restrict__ g, const float* __restrict__ bb,
                       float* __restrict__ xcs, float* __restrict__ ft, float* __restrict__ nrm) {
    int r = blockIdx.x;
    int b = r >> 10, n = r & 1023;
    int o = threadIdx.x;
    const int* id = idx + r * KNN;
    float vmax = -INFINITY, vmin = INFINITY;
    const float* hb = Ht + (size_t)b * NPTS * O + o;
#pragma unroll 4
    for (int k = 0; k < KNN; k++) {
        int m = id[k];                 // broadcast
        float v = hb[(size_t)m * O];   // coalesced across o
        vmax = fmaxf(vmax, v); vmin = fminf(vmin, v);
    }
    float ct = Ct[(size_t)r * O + o];
    float s = g[o] * BN_SC;
    float pre = (s >= 0.f ? vmax : vmin) + ct;
    float out = lrelu(fmaf(s, pre, bb[o]));
    xcs[(size_t)r * XC_C + o] = out;
    if constexpr (WFT) {
        ft[((size_t)b * O + o) * NPTS + n] = out;
        float sq = out * out;
#pragma unroll
        for (int off = 32; off > 0; off >>= 1) sq += __shfl_xor(sq, off);
        __shared__ float red[O/64 > 0 ? O/64 : 1];
        if ((o & 63) == 0) red[o >> 6] = sq;
        __syncthreads();
        if (o == 0) {
            float t = 0.f;
#pragma unroll
            for (int i = 0; i < O/64; i++) t += red[i];
            nrm[r] = t;
        }
    }
}

// ---- split-bf16 conversions for conv5 MFMA ----
__global__ void xcvt_k(const float* __restrict__ xc,
                       unsigned short* __restrict__ xh, unsigned short* __restrict__ xl) {
    int i = blockIdx.x * 256 + threadIdx.x;   // BN*512
    float v = xc[i];
    unsigned short h = f2bf(v);
    xh[i] = h;
    xl[i] = f2bf(v - bf2f(h));
}

__global__ void wcvt_k(const float* __restrict__ w5,
                       unsigned short* __restrict__ wh, unsigned short* __restrict__ wl) {
    int i = blockIdx.x * 256 + threadIdx.x;   // 1024*512, (o,c) row-major kept
    float v = w5[i];
    unsigned short h = f2bf(v);
    wh[i] = h;
    wl[i] = f2bf(v - bf2f(h));
}

// ---- conv5 via LDS-staged split-bf16 MFMA + in-tile max over n (R11, passing, absmax 0.0) ----
__global__ __launch_bounds__(256) void conv5mfma_k(const unsigned short* __restrict__ xh,
                                                   const unsigned short* __restrict__ xl,
                                                   const unsigned short* __restrict__ wh,
                                                   const unsigned short* __restrict__ wl,
                                                   float* __restrict__ part) {
    __shared__ short ah_s[32*72];
    __shared__ short al_s[32*72];
    __shared__ short bh_s[128*72];
    __shared__ short bl_s[128*72];
    int b = blockIdx.z, og = blockIdx.y, nt = blockIdx.x;   // nt 0..31, og 0..7
    int tid = threadIdx.x;
    int w = tid >> 6, lane = tid & 63;
    int m = lane & 15, quad = lane >> 4;
    int h = w >> 1, q = w & 1;
    size_t nbase = (size_t)b * NPTS + nt * 32;
    int obase = og * 128;
    int srow = tid >> 3;          // 0..31
    int scol = (tid & 7) * 8;     // 0,8,...,56 (shorts)

    floatx4 acc[4];
#pragma unroll
    for (int t = 0; t < 4; t++) acc[t] = (floatx4){0.f, 0.f, 0.f, 0.f};

    for (int kc = 0; kc < 512; kc += 64) {
        __syncthreads();   // previous-chunk readers done before overwrite
        *(short8*)(ah_s + srow*72 + scol) = *(const short8*)(xh + (nbase + srow)*512 + kc + scol);
        *(short8*)(al_s + srow*72 + scol) = *(const short8*)(xl + (nbase + srow)*512 + kc + scol);
#pragma unroll
        for (int i = 0; i < 4; i++) {
            int r = srow + i*32;
            *(short8*)(bh_s + r*72 + scol) = *(const short8*)(wh + (size_t)(obase + r)*512 + kc + scol);
            *(short8*)(bl_s + r*72 + scol) = *(const short8*)(wl + (size_t)(obase + r)*512 + kc + scol);
        }
        __syncthreads();
#pragma unroll
        for (int kk = 0; kk < 2; kk++) {
            short8 ah8 = *(const short8*)(ah_s + (h*16 + m)*72 + kk*32 + quad*8);
            short8 al8 = *(const short8*)(al_s + (h*16 + m)*72 + kk*32 + quad*8);
#pragma unroll
            for (int t = 0; t < 4; t++) {
                short8 bh8 = *(const short8*)(bh_s + (q*64 + t*16 + m)*72 + kk*32 + quad*8);
                short8 bl8 = *(const short8*)(bl_s + (q*64 + t*16 + m)*72 + kk*32 + quad*8);
                acc[t] = __builtin_amdgcn_mfma_f32_16x16x32_bf16(ah8, bh8, acc[t], 0, 0, 0);
                acc[t] = __builtin_amdgcn_mfma_f32_16x16x32_bf16(ah8, bl8, acc[t], 0, 0, 0);
                acc[t] = __builtin_amdgcn_mfma_f32_16x16x32_bf16(al8, bh8, acc[t], 0, 0, 0);
            }
        }
    }
#pragma unroll
    for (int t = 0; t < 4; t++) {
        float v = fmaxf(fmaxf(acc[t][0], acc[t][1]), fmaxf(acc[t][2], acc[t][3]));
        v = fmaxf(v, __shfl_xor(v, 16));
        v = fmaxf(v, __shfl_xor(v, 32));
        if (quad == 0)
            part[((size_t)b * 64 + nt*2 + h) * 1024 + obase + q*64 + t*16 + m] = v;
    }
}

// ---- global max pool: gp[b,o] = max_j part[b,j,o] ----
__global__ void gpool_k(const float* __restrict__ part, float* __restrict__ gp) {
    int i = blockIdx.x * 256 + threadIdx.x;   // b*1024+o
    int b = i >> 10, o = i & 1023;
    const float* pb = part + (size_t)b * 64 * 1024 + o;
    float m = pb[0];
#pragma unroll 4
    for (int j = 1; j < 64; j++) m = fmaxf(m, pb[(size_t)j * 1024]);
    gp[i] = m;
}

// ---- linear layer, one wave per output dot ----
template<int C, bool HASBIAS, bool ACT>
__global__ __launch_bounds__(256) void lin_k(const float* __restrict__ X, int xs,
                                             const float* __restrict__ W,
                                             const float* __restrict__ bias,
                                             const float* __restrict__ g, const float* __restrict__ bb,
                                             float* __restrict__ Y, int ys) {
    int wid = (blockIdx.x * 256 + threadIdx.x) >> 6;
    int lane = threadIdx.x & 63;
    int o = wid >> 3;          // NB = 8
    int b = wid & 7;
    const float4* wr = (const float4*)(W + (size_t)o * C);
    const float4* xr = (const float4*)(X + (size_t)b * xs);
    float acc = 0.f;
#pragma unroll
    for (int i = 0; i < C/256; i++) {
        float4 w = wr[lane + 64*i];
        float4 xv = xr[lane + 64*i];
        acc = fmaf(w.x,xv.x, fmaf(w.y,xv.y, fmaf(w.z,xv.z, fmaf(w.w,xv.w, acc))));
    }
#pragma unroll
    for (int off = 32; off > 0; off >>= 1) acc += __shfl_xor(acc, off);
    if (lane == 0) {
        if constexpr (HASBIAS) acc += bias[o];
        if constexpr (ACT) acc = lrelu(fmaf(acc, g[o] * BN_SC, bb[o]));
        Y[(size_t)b * ys + o] = acc;
    }
}

extern "C" void kernel_launch(void* const* d_in, const int* in_sizes, int n_in,
                              void* d_out, int out_size, void* d_ws, size_t ws_size,
                              hipStream_t stream) {
    const float* x       = (const float*)d_in[0];
    const float* conv1_w = (const float*)d_in[1];
    const float* conv1_b = (const float*)d_in[2];
    const float* bn1_g   = (const float*)d_in[3];
    const float* bn1_b   = (const float*)d_in[4];
    const float* conv2_w = (const float*)d_in[5];
    const float* bn2_g   = (const float*)d_in[6];
    const float* bn2_b   = (const float*)d_in[7];
    const float* conv3_w = (const float*)d_in[8];
    const float* bn3_g   = (const float*)d_in[9];
    const float* bn3_b   = (const float*)d_in[10];
    const float* conv4_w = (const float*)d_in[11];
    const float* bn4_g   = (const float*)d_in[12];
    const float* bn4_b   = (const float*)d_in[13];
    const float* conv5_w = (const float*)d_in[14];
    const float* lin1_w  = (const float*)d_in[15];
    const float* bn6_g   = (const float*)d_in[16];
    const float* bn6_b   = (const float*)d_in[17];
    const float* lin2_w  = (const float*)d_in[18];
    const float* lin2_b  = (const float*)d_in[19];
    const float* bn7_g   = (const float*)d_in[20];
    const float* bn7_b   = (const float*)d_in[21];
    const float* lin3_w  = (const float*)d_in[22];
    const float* lin3_b  = (const float*)d_in[23];
    float* outp = (float*)d_out;

    // workspace layout (floats): total 10,657,792 f = 42.6 MB
    float* ws   = (float*)d_ws;
    float* xc   = ws;                          // (BN,512)          4,194,304
    int*   idxb = (int*)(ws + 4194304);        // (BN,20)             163,840
    float* nrm  = ws + 4194304 + 163840;       // (BN)                  8,192
    float* ft   = nrm + 8192;                  // (B,<=128,N)       1,048,576
    float* part = ft + 1048576;                // (B,64,1024)         524,288
    float* w5t  = part + 524288;               // bf16 wh/wl          524,288
    float* Ht   = w5t + 524288;                // (BN,<=256) / xh   2,097,152
    float* Ct   = Ht + 2097152;                // (BN,<=256) / xl   2,097,152
    // head scratch aliases ft (dead after the last knn_k):
    float* gp   = ft;                          // (8,1024)
    float* y1   = ft + 8192;                   // (8,512)
    float* y2   = ft + 8192 + 4096;            // (8,256)
    // split-bf16 aliases (dead regions after stage 4):
    unsigned short* xhp = (unsigned short*)Ht;       // BN*512 shorts
    unsigned short* xlp = (unsigned short*)Ct;
    unsigned short* whp = (unsigned short*)w5t;      // 1024*512 shorts
    unsigned short* wlp = whp + 1024*512;

    prep_k<<<BN/256, 256, 0, stream>>>(x, ft, nrm);

    // Stage 1: C=3 (coords), O=64, with conv bias
    knn_k<3><<<BN/8, 256, 0, stream>>>(ft, x, 3, nrm, idxb);
    hc_k<3, 64, true><<<BN/4, 64, 0, stream>>>(x, 3, conv1_w, conv1_b, Ht, Ct);
    gmax_k<64, true><<<BN, 64, 0, stream>>>(Ht, Ct, idxb, bn1_g, bn1_b, xc + 0, ft, nrm);

    // Stage 2: C=64 -> O=64
    knn_k<64><<<BN/8, 256, 0, stream>>>(ft, xc + 0, XC_C, nrm, idxb);
    hc_k<64, 64, false><<<BN/4, 64, 0, stream>>>(xc + 0, XC_C, conv2_w, nullptr, Ht, Ct);
    gmax_k<64, true><<<BN, 64, 0, stream>>>(Ht, Ct, idxb, bn2_g, bn2_b, xc + 64, ft, nrm);

    // Stage 3: C=64 -> O=128
    knn_k<64><<<BN/8, 256, 0, stream>>>(ft, xc + 64, XC_C, nrm, idxb);
    hc_k<64, 128, false><<<BN/4, 128, 0, stream>>>(xc + 64, XC_C, conv3_w, nullptr, Ht, Ct);
    gmax_k<128, true><<<BN, 128, 0, stream>>>(Ht, Ct, idxb, bn3_g, bn3_b, xc + 128, ft, nrm);

    // Stage 4: C=128 -> O=256 (no next knn)
    knn_k<128><<<BN/8, 256, 0, stream>>>(ft, xc + 128, XC_C, nrm, idxb);
    hc_k<128, 256, false><<<BN/4, 256, 0, stream>>>(xc + 128, XC_C, conv4_w, nullptr, Ht, Ct);
    gmax_k<256, false><<<BN, 256, 0, stream>>>(Ht, Ct, idxb, bn4_g, bn4_b, xc + 256, nullptr, nullptr);

    // conv5 via LDS-staged split-bf16 MFMA + global max pool + parallel head
    xcvt_k<<<BN*512/256, 256, 0, stream>>>(xc, xhp, xlp);
    wcvt_k<<<1024*512/256, 256, 0, stream>>>(conv5_w, whp, wlp);
    conv5mfma_k<<<dim3(32, 8, NB), 256, 0, stream>>>(xhp, xlp, whp, wlp, part);
    gpool_k<<<NB*1024/256, 256, 0, stream>>>(part, gp);
    lin_k<1024, false, true><<<NB*512/4, 256, 0, stream>>>(gp, 1024, lin1_w, nullptr, bn6_g, bn6_b, y1, 512);
    lin_k<512,  true,  true><<<NB*256/4, 256, 0, stream>>>(y1, 512, lin2_w, lin2_b, bn7_g, bn7_b, y2, 256);
    lin_k<256,  true, false><<<NB*40/4,  256, 0, stream>>>(y2, 256, lin3_w, lin3_b, nullptr, nullptr, outp, 40);
}

// Round 15
// 534.529 us; speedup vs baseline: 1.1634x; 1.0822x over previous
//
#include <hip/hip_runtime.h>
#include <cmath>
#include <cstdint>
#include <cstddef>

#define NB 8
#define NPTS 1024
#define BN (NB*NPTS)
#define KNN 20
#define XC_C 512
#define BN_SC 0.99999500003749973f  // 1/sqrt(1+1e-5)

static __device__ __forceinline__ float lrelu(float z) { return z >= 0.f ? z : 0.01f * z; }

// Interleaved DPP max step for TWO independent (lo,hi) u64 chains — R2/R12-validated on HW.
// CTRL: row_ror:1/2/4/8 = 0x121/0x122/0x124/0x128, row_bcast15=0x142, row_bcast31=0x143.
// bound_ctrl=false + old=0 -> lanes with no source contribute 0 (= -inf sentinel).
template<int CTRL>
static __device__ __forceinline__ void dpp_max2(unsigned& loA, unsigned& hiA,
                                                unsigned& loB, unsigned& hiB) {
    unsigned tlA = (unsigned)__builtin_amdgcn_update_dpp(0, (int)loA, CTRL, 0xF, 0xF, false);
    unsigned thA = (unsigned)__builtin_amdgcn_update_dpp(0, (int)hiA, CTRL, 0xF, 0xF, false);
    unsigned tlB = (unsigned)__builtin_amdgcn_update_dpp(0, (int)loB, CTRL, 0xF, 0xF, false);
    unsigned thB = (unsigned)__builtin_amdgcn_update_dpp(0, (int)hiB, CTRL, 0xF, 0xF, false);
    unsigned long long a = ((unsigned long long)hiA << 32) | loA;
    unsigned long long b = ((unsigned long long)thA << 32) | tlA;
    if (b > a) { loA = tlA; hiA = thA; }
    unsigned long long c = ((unsigned long long)hiB << 32) | loB;
    unsigned long long d = ((unsigned long long)thB << 32) | tlB;
    if (d > c) { loB = tlB; hiB = thB; }
}

static __device__ __forceinline__ void wave_max_u64_x2(unsigned long long vA, unsigned long long vB,
                                                       unsigned long long& winA, unsigned long long& winB) {
    unsigned loA = (unsigned)vA, hiA = (unsigned)(vA >> 32);
    unsigned loB = (unsigned)vB, hiB = (unsigned)(vB >> 32);
    dpp_max2<0x121>(loA, hiA, loB, hiB);
    dpp_max2<0x122>(loA, hiA, loB, hiB);
    dpp_max2<0x124>(loA, hiA, loB, hiB);
    dpp_max2<0x128>(loA, hiA, loB, hiB);
    dpp_max2<0x142>(loA, hiA, loB, hiB);   // row_bcast15
    dpp_max2<0x143>(loA, hiA, loB, hiB);   // row_bcast31; lane63 = wave max
    unsigned wloA = (unsigned)__builtin_amdgcn_readlane((int)loA, 63);
    unsigned whiA = (unsigned)__builtin_amdgcn_readlane((int)hiA, 63);
    unsigned wloB = (unsigned)__builtin_amdgcn_readlane((int)loB, 63);
    unsigned whiB = (unsigned)__builtin_amdgcn_readlane((int)hiB, 63);
    winA = ((unsigned long long)whiA << 32) | wloA;
    winB = ((unsigned long long)whiB << 32) | wloB;
}

// ---- bf16 split helpers (RNE) ----
static __device__ __forceinline__ unsigned short f2bf(float f) {
    unsigned u = __float_as_uint(f);
    unsigned r = u + 0x7fffu + ((u >> 16) & 1u);
    return (unsigned short)(r >> 16);
}
static __device__ __forceinline__ float bf2f(unsigned short h) {
    return __uint_as_float(((unsigned)h) << 16);
}

typedef __attribute__((ext_vector_type(8))) short short8;
typedef __attribute__((ext_vector_type(4))) float floatx4;

// ---- prep: x (B,N,3) -> ft (B,3,N) + norms ----
__global__ void prep_k(const float* __restrict__ x, float* __restrict__ ft, float* __restrict__ nrm) {
    int i = blockIdx.x * 256 + threadIdx.x;   // b*N+n
    if (i >= BN) return;
    int b = i >> 10, n = i & 1023;
    float a = x[3*i], c = x[3*i+1], d = x[3*i+2];
    float* fb = ft + (size_t)b * 3 * NPTS;
    fb[n] = a; fb[NPTS + n] = c; fb[2*NPTS + n] = d;
    nrm[i] = a*a + c*c + d*d;
}

// ---- fused knn: EXACT R12 structure (557us-validated, absmax 0.0).
// TWO rows per wave; per-lane SORTED lists; per round: proven u64 DPP wave-max on heads
// + head-equality pop + 15-slot shift. Keys: hi = order-preserving u32 of (2*inner-xx[m]),
// lo = 1023-m; all real keys > 0 so 0 is a safe -inf sentinel.
// Pop order = u64 desc == (value desc, m asc) == jax top_k order.
template<int C>
__global__ __launch_bounds__(256) void knn_k(const float* __restrict__ ft,
                                             const float* __restrict__ frow, int frs,
                                             const float* __restrict__ nrm,
                                             int* __restrict__ idx) {
    int w = threadIdx.x >> 6;
    int lane = threadIdx.x & 63;
    int rA = blockIdx.x * 8 + 2 * w;
    int rB = rA + 1;
    int b = rA >> 10;                       // same batch for both rows (8 | 1024)
    const float* ftb = ft + (size_t)b * C * NPTS;

    float4 accA[4], accB[4];
#pragma unroll
    for (int j = 0; j < 4; j++) { accA[j] = make_float4(0.f,0.f,0.f,0.f); accB[j] = make_float4(0.f,0.f,0.f,0.f); }

    if constexpr ((C & 3) == 0) {
        const float4* crA = (const float4*)(frow + (size_t)rA * frs);
        const float4* crB = (const float4*)(frow + (size_t)rB * frs);
        for (int c4 = 0; c4 < C/4; c4++) {
            float4 ctA = crA[c4], ctB = crB[c4];
#pragma unroll
            for (int cc = 0; cc < 4; cc++) {
                float cA = (&ctA.x)[cc], cB = (&ctB.x)[cc];
                const float4* rm = (const float4*)(ftb + (size_t)(4*c4+cc) * NPTS);
#pragma unroll
                for (int j = 0; j < 4; j++) {
                    float4 v = rm[lane + 64*j];          // shared m-stream for both rows
                    accA[j].x = fmaf(cA, v.x, accA[j].x);
                    accA[j].y = fmaf(cA, v.y, accA[j].y);
                    accA[j].z = fmaf(cA, v.z, accA[j].z);
                    accA[j].w = fmaf(cA, v.w, accA[j].w);
                    accB[j].x = fmaf(cB, v.x, accB[j].x);
                    accB[j].y = fmaf(cB, v.y, accB[j].y);
                    accB[j].z = fmaf(cB, v.z, accB[j].z);
                    accB[j].w = fmaf(cB, v.w, accB[j].w);
                }
            }
        }
    } else {
        for (int c = 0; c < C; c++) {
            float cA = frow[(size_t)rA * frs + c];
            float cB = frow[(size_t)rB * frs + c];
            const float4* rm = (const float4*)(ftb + (size_t)c * NPTS);
#pragma unroll
            for (int j = 0; j < 4; j++) {
                float4 v = rm[lane + 64*j];
                accA[j].x = fmaf(cA, v.x, accA[j].x);
                accA[j].y = fmaf(cA, v.y, accA[j].y);
                accA[j].z = fmaf(cA, v.z, accA[j].z);
                accA[j].w = fmaf(cA, v.w, accA[j].w);
                accB[j].x = fmaf(cB, v.x, accB[j].x);
                accB[j].y = fmaf(cB, v.y, accB[j].y);
                accB[j].z = fmaf(cB, v.z, accB[j].z);
                accB[j].w = fmaf(cB, v.w, accB[j].w);
            }
        }
    }

    unsigned long long keyA[16], keyB[16];
    const float4* nm4 = (const float4*)(nrm + b * NPTS);
#pragma unroll
    for (int j = 0; j < 4; j++) {
        float4 nm = nm4[lane + 64*j];                    // shared for both rows
#pragma unroll
        for (int q = 0; q < 4; q++) {
            int m = 4*(lane + 64*j) + q;
            float fA = 2.f * (&accA[j].x)[q] - (&nm.x)[q];
            unsigned uA = __float_as_uint(fA);
            unsigned sA = (unsigned)((int)uA >> 31);
            uA ^= (sA | 0x80000000u);
            keyA[4*j+q] = ((unsigned long long)uA << 32) | (unsigned)(1023 - m);
            float fB = 2.f * (&accB[j].x)[q] - (&nm.x)[q];
            unsigned uB = __float_as_uint(fB);
            unsigned sB = (unsigned)((int)uB >> 31);
            uB ^= (sB | 0x80000000u);
            keyB[4*j+q] = ((unsigned long long)uB << 32) | (unsigned)(1023 - m);
        }
    }

    // bitonic sort both 16-lists descending (R12-validated; constexpr indices)
#pragma unroll
    for (int ksz = 2; ksz <= 16; ksz <<= 1) {
#pragma unroll
        for (int jst = ksz >> 1; jst > 0; jst >>= 1) {
#pragma unroll
            for (int i = 0; i < 16; i++) {
                int l = i ^ jst;
                if (l > i) {
                    bool dsc = (i & ksz) == 0;
                    unsigned long long a = keyA[i], bb = keyA[l];
                    bool swA = dsc ? (a < bb) : (a > bb);
                    if (swA) { keyA[i] = bb; keyA[l] = a; }
                    unsigned long long c = keyB[i], d = keyB[l];
                    bool swB = dsc ? (c < d) : (c > d);
                    if (swB) { keyB[i] = d; keyB[l] = c; }
                }
            }
        }
    }

    int mineA = 0, mineB = 0;
    for (int kk = 0; kk < KNN; kk++) {       // not unrolled
        unsigned long long winA, winB;
        wave_max_u64_x2(keyA[0], keyB[0], winA, winB);   // heads are local maxima
        if (lane == kk) {
            mineA = 1023 - (int)(unsigned)winA;
            mineB = 1023 - (int)(unsigned)winB;
        }
        bool popA = (keyA[0] == winA);        // unique keys -> exactly one lane pops
        bool popB = (keyB[0] == winB);
#pragma unroll
        for (int t = 0; t < 15; t++) {
            keyA[t] = popA ? keyA[t+1] : keyA[t];
            keyB[t] = popB ? keyB[t+1] : keyB[t];
        }
        keyA[15] = popA ? 0ull : keyA[15];
        keyB[15] = popB ? 0ull : keyB[15];
    }
    if (lane < KNN) {
        idx[rA * KNN + lane] = mineA;
        idx[rB * KNN + lane] = mineB;
    }
}

// ---- H/Ct GEMM: Ht[n,o]=F.w1; Ct[n,o]=F.w2 - Ht + bias ----
// grid BN/RPB, block O; RPB rows per block for weight-traffic amortization
// (stage 4 was L2-weight-bound: 512 MB at RPB=4 -> 256 MB at RPB=8).
// Per-output FMA chain unchanged => bit-identical outputs.
template<int C, int O, bool HASB, int RPB>
__global__ void hc_k(const float* __restrict__ F, int FS,
                     const float* __restrict__ w, const float* __restrict__ bias,
                     float* __restrict__ Ht, float* __restrict__ Ct) {
    int r0 = blockIdx.x * RPB;
    int o = threadIdx.x;
    const float* wr = w + (size_t)o * (2*C);
    float h[RPB], a2[RPB];
#pragma unroll
    for (int nn = 0; nn < RPB; nn++) { h[nn] = 0.f; a2[nn] = 0.f; }
    if constexpr ((C & 3) == 0) {
        const float4* w1 = (const float4*)wr;
        const float4* w2 = (const float4*)(wr + C);
#pragma unroll 4
        for (int c4 = 0; c4 < C/4; c4++) {
            float4 wa = w1[c4], wb = w2[c4];
#pragma unroll
            for (int nn = 0; nn < RPB; nn++) {
                float4 f = *(const float4*)(F + (size_t)(r0+nn)*FS + 4*c4);  // broadcast
                h[nn]  = fmaf(wa.x,f.x, fmaf(wa.y,f.y, fmaf(wa.z,f.z, fmaf(wa.w,f.w, h[nn]))));
                a2[nn] = fmaf(wb.x,f.x, fmaf(wb.y,f.y, fmaf(wb.z,f.z, fmaf(wb.w,f.w, a2[nn]))));
            }
        }
    } else {
        for (int c = 0; c < C; c++) {
            float wa = wr[c], wb = wr[C+c];
#pragma unroll
            for (int nn = 0; nn < RPB; nn++) {
                float f = F[(size_t)(r0+nn)*FS + c];
                h[nn]  = fmaf(wa, f, h[nn]);
                a2[nn] = fmaf(wb, f, a2[nn]);
            }
        }
    }
    float bs = 0.f;
    if constexpr (HASB) bs = bias[o];
#pragma unroll
    for (int nn = 0; nn < RPB; nn++) {
        size_t ro = (size_t)(r0+nn)*O + o;
        Ht[ro] = h[nn];
        Ct[ro] = a2[nn] - h[nn] + bs;
    }
}

// ---- gather + max_k + bn + lrelu; optional transposed-feature + norms for next knn ----
template<int O, bool WFT>
__global__ void gmax_k(const float* __restrict__ Ht, const float* __restrict__ Ct,
                       const int* __restrict__ idx,
                       const float* __restrict__ g, const float* __restrict__ bb,
                       float* __restrict__ xcs, float* __restrict__ ft, float* __restrict__ nrm) {
    int r = blockIdx.x;
    int b = r >> 10, n = r & 1023;
    int o = threadIdx.x;
    const int* id = idx + r * KNN;
    float vmax = -INFINITY, vmin = INFINITY;
    const float* hb = Ht + (size_t)b * NPTS * O + o;
#pragma unroll 4
    for (int k = 0; k < KNN; k++) {
        int m = id[k];                 // broadcast
        float v = hb[(size_t)m * O];   // coalesced across o
        vmax = fmaxf(vmax, v); vmin = fminf(vmin, v);
    }
    float ct = Ct[(size_t)r * O + o];
    float s = g[o] * BN_SC;
    float pre = (s >= 0.f ? vmax : vmin) + ct;
    float out = lrelu(fmaf(s, pre, bb[o]));
    xcs[(size_t)r * XC_C + o] = out;
    if constexpr (WFT) {
        ft[((size_t)b * O + o) * NPTS + n] = out;
        float sq = out * out;
#pragma unroll
        for (int off = 32; off > 0; off >>= 1) sq += __shfl_xor(sq, off);
        __shared__ float red[O/64 > 0 ? O/64 : 1];
        if ((o & 63) == 0) red[o >> 6] = sq;
        __syncthreads();
        if (o == 0) {
            float t = 0.f;
#pragma unroll
            for (int i = 0; i < O/64; i++) t += red[i];
            nrm[r] = t;
        }
    }
}

// ---- split-bf16 conversions for conv5 MFMA ----
__global__ void xcvt_k(const float* __restrict__ xc,
                       unsigned short* __restrict__ xh, unsigned short* __restrict__ xl) {
    int i = blockIdx.x * 256 + threadIdx.x;   // BN*512
    float v = xc[i];
    unsigned short h = f2bf(v);
    xh[i] = h;
    xl[i] = f2bf(v - bf2f(h));
}

__global__ void wcvt_k(const float* __restrict__ w5,
                       unsigned short* __restrict__ wh, unsigned short* __restrict__ wl) {
    int i = blockIdx.x * 256 + threadIdx.x;   // 1024*512, (o,c) row-major kept
    float v = w5[i];
    unsigned short h = f2bf(v);
    wh[i] = h;
    wl[i] = f2bf(v - bf2f(h));
}

// ---- conv5 via LDS-staged split-bf16 MFMA + in-tile max over n (R11-validated, absmax 0.0) ----
__global__ __launch_bounds__(256) void conv5mfma_k(const unsigned short* __restrict__ xh,
                                                   const unsigned short* __restrict__ xl,
                                                   const unsigned short* __restrict__ wh,
                                                   const unsigned short* __restrict__ wl,
                                                   float* __restrict__ part) {
    __shared__ short ah_s[32*72];
    __shared__ short al_s[32*72];
    __shared__ short bh_s[128*72];
    __shared__ short bl_s[128*72];
    int b = blockIdx.z, og = blockIdx.y, nt = blockIdx.x;   // nt 0..31, og 0..7
    int tid = threadIdx.x;
    int w = tid >> 6, lane = tid & 63;
    int m = lane & 15, quad = lane >> 4;
    int h = w >> 1, q = w & 1;
    size_t nbase = (size_t)b * NPTS + nt * 32;
    int obase = og * 128;
    int srow = tid >> 3;          // 0..31
    int scol = (tid & 7) * 8;     // 0,8,...,56 (shorts)

    floatx4 acc[4];
#pragma unroll
    for (int t = 0; t < 4; t++) acc[t] = (floatx4){0.f, 0.f, 0.f, 0.f};

    for (int kc = 0; kc < 512; kc += 64) {
        __syncthreads();   // previous-chunk readers done before overwrite
        *(short8*)(ah_s + srow*72 + scol) = *(const short8*)(xh + (nbase + srow)*512 + kc + scol);
        *(short8*)(al_s + srow*72 + scol) = *(const short8*)(xl + (nbase + srow)*512 + kc + scol);
#pragma unroll
        for (int i = 0; i < 4; i++) {
            int r = srow + i*32;
            *(short8*)(bh_s + r*72 + scol) = *(const short8*)(wh + (size_t)(obase + r)*512 + kc + scol);
            *(short8*)(bl_s + r*72 + scol) = *(const short8*)(wl + (size_t)(obase + r)*512 + kc + scol);
        }
        __syncthreads();
#pragma unroll
        for (int kk = 0; kk < 2; kk++) {
            short8 ah8 = *(const short8*)(ah_s + (h*16 + m)*72 + kk*32 + quad*8);
            short8 al8 = *(const short8*)(al_s + (h*16 + m)*72 + kk*32 + quad*8);
#pragma unroll
            for (int t = 0; t < 4; t++) {
                short8 bh8 = *(const short8*)(bh_s + (q*64 + t*16 + m)*72 + kk*32 + quad*8);
                short8 bl8 = *(const short8*)(bl_s + (q*64 + t*16 + m)*72 + kk*32 + quad*8);
                acc[t] = __builtin_amdgcn_mfma_f32_16x16x32_bf16(ah8, bh8, acc[t], 0, 0, 0);
                acc[t] = __builtin_amdgcn_mfma_f32_16x16x32_bf16(ah8, bl8, acc[t], 0, 0, 0);
                acc[t] = __builtin_amdgcn_mfma_f32_16x16x32_bf16(al8, bh8, acc[t], 0, 0, 0);
            }
        }
    }
#pragma unroll
    for (int t = 0; t < 4; t++) {
        float v = fmaxf(fmaxf(acc[t][0], acc[t][1]), fmaxf(acc[t][2], acc[t][3]));
        v = fmaxf(v, __shfl_xor(v, 16));
        v = fmaxf(v, __shfl_xor(v, 32));
        if (quad == 0)
            part[((size_t)b * 64 + nt*2 + h) * 1024 + obase + q*64 + t*16 + m] = v;
    }
}

// ---- global max pool: gp[b,o] = max_j part[b,j,o] ----
__global__ void gpool_k(const float* __restrict__ part, float* __restrict__ gp) {
    int i = blockIdx.x * 256 + threadIdx.x;   // b*1024+o
    int b = i >> 10, o = i & 1023;
    const float* pb = part + (size_t)b * 64 * 1024 + o;
    float m = pb[0];
#pragma unroll 4
    for (int j = 1; j < 64; j++) m = fmaxf(m, pb[(size_t)j * 1024]);
    gp[i] = m;
}

// ---- linear layer, one wave per output dot ----
template<int C, bool HASBIAS, bool ACT>
__global__ __launch_bounds__(256) void lin_k(const float* __restrict__ X, int xs,
                                             const float* __restrict__ W,
                                             const float* __restrict__ bias,
                                             const float* __restrict__ g, const float* __restrict__ bb,
                                             float* __restrict__ Y, int ys) {
    int wid = (blockIdx.x * 256 + threadIdx.x) >> 6;
    int lane = threadIdx.x & 63;
    int o = wid >> 3;          // NB = 8
    int b = wid & 7;
    const float4* wr = (const float4*)(W + (size_t)o * C);
    const float4* xr = (const float4*)(X + (size_t)b * xs);
    float acc = 0.f;
#pragma unroll
    for (int i = 0; i < C/256; i++) {
        float4 w = wr[lane + 64*i];
        float4 xv = xr[lane + 64*i];
        acc = fmaf(w.x,xv.x, fmaf(w.y,xv.y, fmaf(w.z,xv.z, fmaf(w.w,xv.w, acc))));
    }
#pragma unroll
    for (int off = 32; off > 0; off >>= 1) acc += __shfl_xor(acc, off);
    if (lane == 0) {
        if constexpr (HASBIAS) acc += bias[o];
        if constexpr (ACT) acc = lrelu(fmaf(acc, g[o] * BN_SC, bb[o]));
        Y[(size_t)b * ys + o] = acc;
    }
}

extern "C" void kernel_launch(void* const* d_in, const int* in_sizes, int n_in,
                              void* d_out, int out_size, void* d_ws, size_t ws_size,
                              hipStream_t stream) {
    const float* x       = (const float*)d_in[0];
    const float* conv1_w = (const float*)d_in[1];
    const float* conv1_b = (const float*)d_in[2];
    const float* bn1_g   = (const float*)d_in[3];
    const float* bn1_b   = (const float*)d_in[4];
    const float* conv2_w = (const float*)d_in[5];
    const float* bn2_g   = (const float*)d_in[6];
    const float* bn2_b   = (const float*)d_in[7];
    const float* conv3_w = (const float*)d_in[8];
    const float* bn3_g   = (const float*)d_in[9];
    const float* bn3_b   = (const float*)d_in[10];
    const float* conv4_w = (const float*)d_in[11];
    const float* bn4_g   = (const float*)d_in[12];
    const float* bn4_b   = (const float*)d_in[13];
    const float* conv5_w = (const float*)d_in[14];
    const float* lin1_w  = (const float*)d_in[15];
    const float* bn6_g   = (const float*)d_in[16];
    const float* bn6_b   = (const float*)d_in[17];
    const float* lin2_w  = (const float*)d_in[18];
    const float* lin2_b  = (const float*)d_in[19];
    const float* bn7_g   = (const float*)d_in[20];
    const float* bn7_b   = (const float*)d_in[21];
    const float* lin3_w  = (const float*)d_in[22];
    const float* lin3_b  = (const float*)d_in[23];
    float* outp = (float*)d_out;

    // workspace layout (floats): total 10,657,792 f = 42.6 MB
    float* ws   = (float*)d_ws;
    float* xc   = ws;                          // (BN,512)          4,194,304
    int*   idxb = (int*)(ws + 4194304);        // (BN,20)             163,840
    float* nrm  = ws + 4194304 + 163840;       // (BN)                  8,192
    float* ft   = nrm + 8192;                  // (B,<=128,N)       1,048,576
    float* part = ft + 1048576;                // (B,64,1024)         524,288
    float* w5t  = part + 524288;               // bf16 wh/wl          524,288
    float* Ht   = w5t + 524288;                // (BN,<=256) / xh   2,097,152
    float* Ct   = Ht + 2097152;                // (BN,<=256) / xl   2,097,152
    // head scratch aliases ft (dead after the last knn_k):
    float* gp   = ft;                          // (8,1024)
    float* y1   = ft + 8192;                   // (8,512)
    float* y2   = ft + 8192 + 4096;            // (8,256)
    // split-bf16 aliases (dead regions after stage 4):
    unsigned short* xhp = (unsigned short*)Ht;       // BN*512 shorts
    unsigned short* xlp = (unsigned short*)Ct;
    unsigned short* whp = (unsigned short*)w5t;      // 1024*512 shorts
    unsigned short* wlp = whp + 1024*512;

    prep_k<<<BN/256, 256, 0, stream>>>(x, ft, nrm);

    // Stage 1: C=3 (coords), O=64, with conv bias
    knn_k<3><<<BN/8, 256, 0, stream>>>(ft, x, 3, nrm, idxb);
    hc_k<3, 64, true, 4><<<BN/4, 64, 0, stream>>>(x, 3, conv1_w, conv1_b, Ht, Ct);
    gmax_k<64, true><<<BN, 64, 0, stream>>>(Ht, Ct, idxb, bn1_g, bn1_b, xc + 0, ft, nrm);

    // Stage 2: C=64 -> O=64
    knn_k<64><<<BN/8, 256, 0, stream>>>(ft, xc + 0, XC_C, nrm, idxb);
    hc_k<64, 64, false, 4><<<BN/4, 64, 0, stream>>>(xc + 0, XC_C, conv2_w, nullptr, Ht, Ct);
    gmax_k<64, true><<<BN, 64, 0, stream>>>(Ht, Ct, idxb, bn2_g, bn2_b, xc + 64, ft, nrm);

    // Stage 3: C=64 -> O=128
    knn_k<64><<<BN/8, 256, 0, stream>>>(ft, xc + 64, XC_C, nrm, idxb);
    hc_k<64, 128, false, 4><<<BN/4, 128, 0, stream>>>(xc + 64, XC_C, conv3_w, nullptr, Ht, Ct);
    gmax_k<128, true><<<BN, 128, 0, stream>>>(Ht, Ct, idxb, bn3_g, bn3_b, xc + 128, ft, nrm);

    // Stage 4: C=128 -> O=256 (no next knn); RPB=8 halves conv4_w L2 traffic (512->256 MB)
    knn_k<128><<<BN/8, 256, 0, stream>>>(ft, xc + 128, XC_C, nrm, idxb);
    hc_k<128, 256, false, 8><<<BN/8, 256, 0, stream>>>(xc + 128, XC_C, conv4_w, nullptr, Ht, Ct);
    gmax_k<256, false><<<BN, 256, 0, stream>>>(Ht, Ct, idxb, bn4_g, bn4_b, xc + 256, nullptr, nullptr);

    // conv5 via LDS-staged split-bf16 MFMA + global max pool + parallel head
    xcvt_k<<<BN*512/256, 256, 0, stream>>>(xc, xhp, xlp);
    wcvt_k<<<1024*512/256, 256, 0, stream>>>(conv5_w, whp, wlp);
    conv5mfma_k<<<dim3(32, 8, NB), 256, 0, stream>>>(xhp, xlp, whp, wlp, part);
    gpool_k<<<NB*1024/256, 256, 0, stream>>>(part, gp);
    lin_k<1024, false, true><<<NB*512/4, 256, 0, stream>>>(gp, 1024, lin1_w, nullptr, bn6_g, bn6_b, y1, 512);
    lin_k<512,  true,  true><<<NB*256/4, 256, 0, stream>>>(y1, 512, lin2_w, lin2_b, bn7_g, bn7_b, y2, 256);
    lin_k<256,  true, false><<<NB*40/4,  256, 0, stream>>>(y2, 256, lin3_w, lin3_b, nullptr, nullptr, outp, 40);
}